// Round 11
// baseline (385.344 us; speedup 1.0000x reference)
//
#include <hip/hip_runtime.h>
#include <math.h>

#define NN     50000
#define FF     256
#define HH     64
#define NHEADS 4
#define EE     800000
#define OUTD   16

typedef __attribute__((ext_vector_type(8))) short short8;
typedef __attribute__((ext_vector_type(4))) float f32x4;

#define GAS __attribute__((address_space(1)))
#define LAS __attribute__((address_space(3)))

__device__ inline unsigned short f2bf(float f) {
    unsigned u = __builtin_bit_cast(unsigned, f);
    unsigned r = (u + 0x7fff + ((u >> 16) & 1)) >> 16;
    return (unsigned short)r;
}
__device__ inline float bf2f(unsigned short s) {
    unsigned u = ((unsigned)s) << 16;
    return __builtin_bit_cast(float, u);
}

// ---------------------------------------------------------------------------
// CSR build (3-phase hierarchical scan — round-4 lesson).
// ---------------------------------------------------------------------------
__global__ void k_zero_int(int* __restrict__ p, int n) {
    int i = blockIdx.x * blockDim.x + threadIdx.x;
    if (i < n) p[i] = 0;
}

__global__ void k_count(const int* __restrict__ dst, int* __restrict__ cnt, int e) {
    int i = blockIdx.x * blockDim.x + threadIdx.x;
    if (i < e) atomicAdd(&cnt[dst[i]], 1);
}

__global__ __launch_bounds__(256) void k_scan_a(const int* __restrict__ cnt,
                                                int* __restrict__ partial, int n) {
    int i = blockIdx.x * 256 + threadIdx.x;
    int v = (i < n) ? cnt[i] : 0;
#pragma unroll
    for (int off = 32; off >= 1; off >>= 1) v += __shfl_xor(v, off, 64);
    __shared__ int ws[4];
    int wave = threadIdx.x >> 6;
    if ((threadIdx.x & 63) == 0) ws[wave] = v;
    __syncthreads();
    if (threadIdx.x == 0) partial[blockIdx.x] = ws[0] + ws[1] + ws[2] + ws[3];
}

__global__ __launch_bounds__(256) void k_scan_b(const int* __restrict__ partial,
                                                int* __restrict__ blockoff,
                                                int* __restrict__ total_out, int nb) {
    __shared__ int arr[256];
    int tid = threadIdx.x;
    arr[tid] = (tid < nb) ? partial[tid] : 0;
    __syncthreads();
#pragma unroll
    for (int off = 1; off < 256; off <<= 1) {
        int v = arr[tid];
        int add = (tid >= off) ? arr[tid - off] : 0;
        __syncthreads();
        arr[tid] = v + add;
        __syncthreads();
    }
    if (tid < nb) blockoff[tid] = arr[tid] - partial[tid];
    if (tid == 0) *total_out = arr[255];
}

__global__ __launch_bounds__(256) void k_scan_c(const int* __restrict__ cnt,
                                                const int* __restrict__ blockoff,
                                                int* __restrict__ row_start,
                                                int* __restrict__ cursor,
                                                float* __restrict__ dinv, int n) {
    __shared__ int arr[256];
    int tid = threadIdx.x;
    int i = blockIdx.x * 256 + tid;
    int c = (i < n) ? cnt[i] : 0;
    arr[tid] = c;
    __syncthreads();
#pragma unroll
    for (int off = 1; off < 256; off <<= 1) {
        int v = arr[tid];
        int add = (tid >= off) ? arr[tid - off] : 0;
        __syncthreads();
        arr[tid] = v + add;
        __syncthreads();
    }
    if (i < n) {
        int excl = arr[tid] - c + blockoff[blockIdx.x];
        row_start[i] = excl;
        cursor[i] = excl;
        dinv[i] = rsqrtf((float)(c + 1));
    }
}

__global__ void k_fill(const int* __restrict__ src, const int* __restrict__ dst,
                       int* __restrict__ cursor, int* __restrict__ col, int e) {
    int i = blockIdx.x * blockDim.x + threadIdx.x;
    if (i < e) {
        int d = dst[i];
        int pos = atomicAdd(&cursor[d], 1);
        col[pos] = src[i];
    }
}

// ---------------------------------------------------------------------------
// Weight packing: all four weights in ONE launch (round-10: 4 tiny kernels
// were 4 launch gaps). Fragment layout as before; hi/lo bf16 split.
// ---------------------------------------------------------------------------
__device__ inline void pack_one(const float* __restrict__ W,
                                unsigned short* __restrict__ bhi,
                                unsigned short* __restrict__ blo,
                                int t_, int NT, int NTOT, int TOFF, int SRC_NC) {
    int lane = t_ & 63;
    int tile = (t_ >> 6) % NT;
    int kb = (t_ >> 6) / NT;
    int q = lane >> 4, c = lane & 15;
    size_t off = ((size_t)(kb * NTOT + TOFF + tile) * 64 + lane) * 8;
#pragma unroll
    for (int j = 0; j < 8; j++) {
        float w = W[(size_t)(kb * 32 + q * 8 + j) * SRC_NC + tile * 16 + c];
        unsigned short h = f2bf(w);
        bhi[off + j] = h;
        blo[off + j] = f2bf(w - bf2f(h));
    }
}

#define NTT 20
__global__ __launch_bounds__(256) void k_pack_all(const float* __restrict__ Wg1,
                                                  const float* __restrict__ Wgat1,
                                                  const float* __restrict__ Wg2,
                                                  const float* __restrict__ Wgat2,
                                                  unsigned short* __restrict__ bhiC,
                                                  unsigned short* __restrict__ bloC,
                                                  unsigned short* __restrict__ bhiG2,
                                                  unsigned short* __restrict__ bloG2,
                                                  unsigned short* __restrict__ bhiA2,
                                                  unsigned short* __restrict__ bloA2) {
    int t = blockIdx.x * 256 + threadIdx.x;
    if (t < 2048)        pack_one(Wg1,   bhiC,  bloC,  t,         4,  NTT, 0, 64);
    else if (t < 10240)  pack_one(Wgat1, bhiC,  bloC,  t - 2048,  16, NTT, 4, 256);
    else if (t < 10368)  pack_one(Wg2,   bhiG2, bloG2, t - 10240, 1,  1,   0, 16);
    else if (t < 10880)  pack_one(Wgat2, bhiA2, bloA2, t - 10368, 1,  1,   0, 16);
}

// ---------------------------------------------------------------------------
// FUSED big GEMM (bf16x2): one pass over x -> h1 (4 tiles, dinv-scaled) +
// hgat (16 tiles) + fused s1 scores. Round-10 counters: MfmaUtil 13.8%,
// all pipes idle -> the 40 KB/kb stage behind __syncthreads is the stall.
// Fix: async DMA staging via global_load_lds width=16 (no VGPR round-trip,
// one vmcnt drain at the barrier) — the m93->m97 ladder step.
// ---------------------------------------------------------------------------
__global__ __launch_bounds__(256) void mfma_gemm_fused(const float* __restrict__ A,
                                                       const unsigned short* __restrict__ Bhi,
                                                       const unsigned short* __restrict__ Blo,
                                                       unsigned short* __restrict__ Ch1,
                                                       unsigned short* __restrict__ Chg,
                                                       const float* __restrict__ dinv,
                                                       const float* __restrict__ a_s,
                                                       const float* __restrict__ a_d,
                                                       float* __restrict__ ssrc,
                                                       float* __restrict__ sdst,
                                                       int M) {
    const int K = 256;
    __shared__ short8 bsh[NTT * 64];
    __shared__ short8 bsl[NTT * 64];
    int tid = threadIdx.x;
    int w = tid >> 6, lane = tid & 63, q = lane >> 4, c = lane & 15;
    int row_base = blockIdx.x * 64 + w * 16;
    int ar = min(row_base + c, M - 1);
    const float* ap = A + (size_t)ar * K + q * 8;

    f32x4 acc[NTT];
#pragma unroll
    for (int t = 0; t < NTT; t++) acc[t] = (f32x4){0.f, 0.f, 0.f, 0.f};

    for (int kb = 0; kb < 8; kb++) {
        float av[8];
        *(float4*)(av)     = *(const float4*)(ap + kb * 32);
        *(float4*)(av + 4) = *(const float4*)(ap + kb * 32 + 4);
        short8 ahi, alo;
#pragma unroll
        for (int j = 0; j < 8; j++) {
            unsigned short h = f2bf(av[j]);
            ahi[j] = (short)h;
            alo[j] = (short)f2bf(av[j] - bf2f(h));
        }
        const short8* gh = (const short8*)(Bhi + (size_t)kb * NTT * 512);
        const short8* gl = (const short8*)(Blo + (size_t)kb * NTT * 512);
        __syncthreads();  // readers of previous kb done
#if __has_builtin(__builtin_amdgcn_global_load_lds)
        // per-wave DMA: lptr is wave-uniform base, HW scatters lane*16;
        // gptr is per-lane. 5 hi + 5 lo issues/wave cover 2*1280 short8.
#pragma unroll
        for (int k2 = 0; k2 < 5; k2++) {
            int i = k2 * 256 + w * 64;
            __builtin_amdgcn_global_load_lds(
                (const GAS unsigned char*)(gh + i + lane),
                (LAS unsigned char*)(&bsh[i]), 16, 0, 0);
            __builtin_amdgcn_global_load_lds(
                (const GAS unsigned char*)(gl + i + lane),
                (LAS unsigned char*)(&bsl[i]), 16, 0, 0);
        }
#else
        for (int i = tid; i < NTT * 64; i += 256) {
            bsh[i] = gh[i];
            bsl[i] = gl[i];
        }
#endif
        __syncthreads();  // drains vmcnt (DMA) before LDS reads
#pragma unroll
        for (int t = 0; t < NTT; t++) {
            short8 bhi = bsh[t * 64 + lane];
            short8 blo = bsl[t * 64 + lane];
            acc[t] = __builtin_amdgcn_mfma_f32_16x16x32_bf16(ahi, bhi, acc[t], 0, 0, 0);
            acc[t] = __builtin_amdgcn_mfma_f32_16x16x32_bf16(alo, bhi, acc[t], 0, 0, 0);
            acc[t] = __builtin_amdgcn_mfma_f32_16x16x32_bf16(ahi, blo, acc[t], 0, 0, 0);
        }
    }

    // s1 scores over the 16 GAT tiles (tiles 4..19; head = (t-4)>>2)
#pragma unroll
    for (int i = 0; i < 4; i++) {
        int r = row_base + q * 4 + i;
        float ss[4] = {0.f, 0.f, 0.f, 0.f};
        float sd[4] = {0.f, 0.f, 0.f, 0.f};
#pragma unroll
        for (int t = 0; t < 16; t++) {
            float v = acc[t + 4][i];
            ss[t >> 2] += v * a_s[t * 16 + c];
            sd[t >> 2] += v * a_d[t * 16 + c];
        }
#pragma unroll
        for (int h = 0; h < 4; h++) {
#pragma unroll
            for (int off = 1; off <= 8; off <<= 1) {
                ss[h] += __shfl_xor(ss[h], off, 16);
                sd[h] += __shfl_xor(sd[h], off, 16);
            }
        }
        if (c == i && r < M) {
            *(float4*)(ssrc + (size_t)r * 4) = make_float4(ss[0], ss[1], ss[2], ss[3]);
            *(float4*)(sdst + (size_t)r * 4) = make_float4(sd[0], sd[1], sd[2], sd[3]);
        }
    }

#pragma unroll
    for (int i = 0; i < 4; i++) {
        int r = row_base + q * 4 + i;
        if (r < M) {
            float sc = dinv[r];
#pragma unroll
            for (int t = 0; t < 4; t++)
                Ch1[(size_t)r * 64 + t * 16 + c] = f2bf(acc[t][i] * sc);
#pragma unroll
            for (int t = 0; t < 16; t++)
                Chg[(size_t)r * 256 + t * 16 + c] = f2bf(acc[t + 4][i]);
        }
    }
}

// ---------------------------------------------------------------------------
// MFMA GEMM with N=16, A exact bf16 (K=KB*32). W2 split hi/lo -> 2 MFMAs.
// Output bf16 into the INTERLEAVED pair buffer at [(r*16+c)*2 + OFS].
// ---------------------------------------------------------------------------
template <int KB, bool SCALE, bool SC2, int OFS>
__global__ __launch_bounds__(256) void mfma_n16(const unsigned short* __restrict__ A,
                                                const unsigned short* __restrict__ Bhi,
                                                const unsigned short* __restrict__ Blo,
                                                unsigned short* __restrict__ Cbf,
                                                const float* __restrict__ rowscale,
                                                const float* __restrict__ a_s2,
                                                const float* __restrict__ a_d2,
                                                float* __restrict__ s2s,
                                                float* __restrict__ s2d, int M) {
    const int K = KB * 32;
    int tid = threadIdx.x;
    int w = tid >> 6, lane = tid & 63, q = lane >> 4, c = lane & 15;
    int row_base = blockIdx.x * 64 + w * 16;
    int ar = min(row_base + c, M - 1);
    const unsigned short* ap = A + (size_t)ar * K + q * 8;
    f32x4 acc = (f32x4){0.f, 0.f, 0.f, 0.f};
#pragma unroll
    for (int kb = 0; kb < KB; kb++) {
        short8 av = *(const short8*)(ap + kb * 32);
        size_t bo = ((size_t)kb * 64 + lane) * 8;
        short8 bh = *(const short8*)(Bhi + bo);
        short8 bl = *(const short8*)(Blo + bo);
        acc = __builtin_amdgcn_mfma_f32_16x16x32_bf16(av, bh, acc, 0, 0, 0);
        acc = __builtin_amdgcn_mfma_f32_16x16x32_bf16(av, bl, acc, 0, 0, 0);
    }
    if (SC2) {
#pragma unroll
        for (int i = 0; i < 4; i++) {
            float ps = acc[i] * a_s2[c];
            float pd = acc[i] * a_d2[c];
#pragma unroll
            for (int off = 1; off <= 8; off <<= 1) {
                ps += __shfl_xor(ps, off, 16);
                pd += __shfl_xor(pd, off, 16);
            }
            int r = row_base + q * 4 + i;
            if (c == i && r < M) {
                s2s[r] = ps;
                s2d[r] = pd;
            }
        }
    }
#pragma unroll
    for (int i = 0; i < 4; i++) {
        int r = row_base + q * 4 + i;
        if (r < M) {
            float sc = SCALE ? rowscale[r] : 1.0f;
            Cbf[((size_t)r * 16 + c) * 2 + OFS] = f2bf(acc[i] * sc);
        }
    }
}

// ---------------------------------------------------------------------------
// GCN1 aggregation, h1 bf16, pre-scaled by dinv; out bf16. 16 edges/iter.
// ---------------------------------------------------------------------------
__global__ __launch_bounds__(256) void gcn1_agg(const unsigned short* __restrict__ h,
                                                const int* __restrict__ rs,
                                                const int* __restrict__ col,
                                                const float* __restrict__ dinv,
                                                const float* __restrict__ b,
                                                unsigned short* __restrict__ out) {
    int wid = (blockIdx.x * 256 + threadIdx.x) >> 6;
    int lane = threadIdx.x & 63;
    if (wid >= NN) return;
    int g = lane >> 4;
    int cidx = (lane & 15) * 4;
    float di = dinv[wid];
    int beg = rs[wid], end = rs[wid + 1];
    float4 acc = make_float4(0.f, 0.f, 0.f, 0.f);

    for (int j0 = beg; j0 < end; j0 += 64) {
        int cnt = min(64, end - j0);
        int sreg = 0;
        if (lane < cnt) sreg = col[j0 + lane];
        for (int e = 0; e < cnt; e += 16) {
            int m0 = e + g, m1 = e + g + 4, m2 = e + g + 8, m3 = e + g + 12;
            int s0 = __shfl(sreg, m0, 64);   // unconditional (round-2 lesson)
            int s1 = __shfl(sreg, m1, 64);
            int s2 = __shfl(sreg, m2, 64);
            int s3 = __shfl(sreg, m3, 64);
            ushort4 v0 = make_ushort4(0, 0, 0, 0), v1 = make_ushort4(0, 0, 0, 0);
            ushort4 v2 = make_ushort4(0, 0, 0, 0), v3 = make_ushort4(0, 0, 0, 0);
            if (m0 < cnt) v0 = *(const ushort4*)(h + (size_t)s0 * HH + cidx);
            if (m1 < cnt) v1 = *(const ushort4*)(h + (size_t)s1 * HH + cidx);
            if (m2 < cnt) v2 = *(const ushort4*)(h + (size_t)s2 * HH + cidx);
            if (m3 < cnt) v3 = *(const ushort4*)(h + (size_t)s3 * HH + cidx);
            acc.x += (bf2f(v0.x) + bf2f(v1.x)) + (bf2f(v2.x) + bf2f(v3.x));
            acc.y += (bf2f(v0.y) + bf2f(v1.y)) + (bf2f(v2.y) + bf2f(v3.y));
            acc.z += (bf2f(v0.z) + bf2f(v1.z)) + (bf2f(v2.z) + bf2f(v3.z));
            acc.w += (bf2f(v0.w) + bf2f(v1.w)) + (bf2f(v2.w) + bf2f(v3.w));
        }
    }
#pragma unroll
    for (int off = 16; off <= 32; off <<= 1) {
        acc.x += __shfl_xor(acc.x, off, 64);
        acc.y += __shfl_xor(acc.y, off, 64);
        acc.z += __shfl_xor(acc.z, off, 64);
        acc.w += __shfl_xor(acc.w, off, 64);
    }
    if (g == 0) {
        ushort4 sv = *(const ushort4*)(h + (size_t)wid * HH + cidx);
        float4 bv = *(const float4*)(b + cidx);
        ushort4 o;
        o.x = f2bf(fmaxf((acc.x + bf2f(sv.x)) * di + bv.x, 0.f));
        o.y = f2bf(fmaxf((acc.y + bf2f(sv.y)) * di + bv.y, 0.f));
        o.z = f2bf(fmaxf((acc.z + bf2f(sv.z)) * di + bv.z, 0.f));
        o.w = f2bf(fmaxf((acc.w + bf2f(sv.w)) * di + bv.w, 0.f));
        *(ushort4*)(out + (size_t)wid * HH + cidx) = o;
    }
}

// ---------------------------------------------------------------------------
// GAT1 aggregation: LDS-staged p/src; 4-edge unrolled gather. At its
// fabric-ceiling floor (~3.6 TB/s FETCH-side) — kept unchanged (control).
// ---------------------------------------------------------------------------
__global__ __launch_bounds__(256) void gat1_agg(const unsigned short* __restrict__ hg,
                                                const int* __restrict__ rs,
                                                const int* __restrict__ col,
                                                const float* __restrict__ ssrc,
                                                const float* __restrict__ sdst,
                                                const float* __restrict__ b,
                                                unsigned short* __restrict__ out) {
    __shared__ int s_lds[4][64];
    __shared__ float p_lds[4][64 * 4];
    int tid = threadIdx.x;
    int w = tid >> 6, lane = tid & 63;
    int wid = blockIdx.x * 4 + w;       // grid exact: 12500*4 = NN
    int hh = lane >> 4;
    int* sl = s_lds[w];
    float* pl = p_lds[w];

    float4 sd4 = *(const float4*)(sdst + (size_t)wid * 4);
    float sdv[4] = {sd4.x, sd4.y, sd4.z, sd4.w};
    float4 sf4 = *(const float4*)(ssrc + (size_t)wid * 4);
    float sfv[4] = {sf4.x, sf4.y, sf4.z, sf4.w};
    float psf[4];
#pragma unroll
    for (int h = 0; h < 4; h++) {
        float e = sfv[h] + sdv[h];
        e = (e >= 0.f) ? e : 0.2f * e;
        psf[h] = __expf(e);
    }
    float pse = (hh & 2) ? ((hh & 1) ? psf[3] : psf[2]) : ((hh & 1) ? psf[1] : psf[0]);
    const unsigned short* hbase = hg + lane * 4;
    ushort4 hvs = *(const ushort4*)(hbase + (size_t)wid * 256);
    float4 acc;
    acc.x = bf2f(hvs.x) * pse; acc.y = bf2f(hvs.y) * pse;
    acc.z = bf2f(hvs.z) * pse; acc.w = bf2f(hvs.w) * pse;

    float lsum[4] = {0.f, 0.f, 0.f, 0.f};
    int beg = rs[wid], end = rs[wid + 1];
    for (int j0 = beg; j0 < end; j0 += 64) {
        int cnt = min(64, end - j0);
        if (lane < cnt) {
            int sreg = col[j0 + lane];
            float4 sv = *(const float4*)(ssrc + (size_t)sreg * 4);
            float svv[4] = {sv.x, sv.y, sv.z, sv.w};
            float pv[4];
#pragma unroll
            for (int h = 0; h < 4; h++) {
                float e = svv[h] + sdv[h];
                e = (e >= 0.f) ? e : 0.2f * e;
                pv[h] = __expf(e);
                lsum[h] += pv[h];
            }
            sl[lane] = sreg;
            *(float4*)&pl[lane * 4] = make_float4(pv[0], pv[1], pv[2], pv[3]);
        }
        int e = 0;
        for (; e + 4 <= cnt; e += 4) {
            int s0 = sl[e], s1 = sl[e + 1], s2 = sl[e + 2], s3 = sl[e + 3];
            float p0 = pl[e * 4 + hh], p1 = pl[(e + 1) * 4 + hh];
            float p2 = pl[(e + 2) * 4 + hh], p3 = pl[(e + 3) * 4 + hh];
            ushort4 h0 = *(const ushort4*)(hbase + (size_t)s0 * 256);
            ushort4 h1 = *(const ushort4*)(hbase + (size_t)s1 * 256);
            ushort4 h2 = *(const ushort4*)(hbase + (size_t)s2 * 256);
            ushort4 h3 = *(const ushort4*)(hbase + (size_t)s3 * 256);
            acc.x += bf2f(h0.x) * p0; acc.y += bf2f(h0.y) * p0;
            acc.z += bf2f(h0.z) * p0; acc.w += bf2f(h0.w) * p0;
            acc.x += bf2f(h1.x) * p1; acc.y += bf2f(h1.y) * p1;
            acc.z += bf2f(h1.z) * p1; acc.w += bf2f(h1.w) * p1;
            acc.x += bf2f(h2.x) * p2; acc.y += bf2f(h2.y) * p2;
            acc.z += bf2f(h2.z) * p2; acc.w += bf2f(h2.w) * p2;
            acc.x += bf2f(h3.x) * p3; acc.y += bf2f(h3.y) * p3;
            acc.z += bf2f(h3.z) * p3; acc.w += bf2f(h3.w) * p3;
        }
        for (; e < cnt; e++) {
            int s = sl[e];
            float p = pl[e * 4 + hh];
            ushort4 hv = *(const ushort4*)(hbase + (size_t)s * 256);
            acc.x += bf2f(hv.x) * p; acc.y += bf2f(hv.y) * p;
            acc.z += bf2f(hv.z) * p; acc.w += bf2f(hv.w) * p;
        }
    }
#pragma unroll
    for (int h = 0; h < 4; h++) {
        float v = lsum[h];
        for (int off = 32; off >= 1; off >>= 1) v += __shfl_xor(v, off, 64);
        lsum[h] = v + psf[h];
    }
    float lt = (hh & 2) ? ((hh & 1) ? lsum[3] : lsum[2]) : ((hh & 1) ? lsum[1] : lsum[0]);
    float li = 1.0f / lt;
    float4 bv = *(const float4*)(b + lane * 4);
    ushort4 o;
    o.x = f2bf(fmaxf(acc.x * li + bv.x, 0.f));
    o.y = f2bf(fmaxf(acc.y * li + bv.y, 0.f));
    o.z = f2bf(fmaxf(acc.z * li + bv.z, 0.f));
    o.w = f2bf(fmaxf(acc.w * li + bv.w, 0.f));
    *(ushort4*)(out + (size_t)wid * 256 + lane * 4) = o;
}

// ---------------------------------------------------------------------------
// Final aggregation: fused GCN2 + GAT2 over the interleaved pair buffer.
// ---------------------------------------------------------------------------
__global__ __launch_bounds__(256) void final_agg(const unsigned* __restrict__ hp,
                                                 const int* __restrict__ rs,
                                                 const int* __restrict__ col,
                                                 const float* __restrict__ dinv,
                                                 const float* __restrict__ s2s,
                                                 const float* __restrict__ s2d,
                                                 const float* __restrict__ bg2,
                                                 const float* __restrict__ bga2,
                                                 float* __restrict__ out) {
    int t = blockIdx.x * 256 + threadIdx.x;
    int node = t >> 4;
    int c = t & 15;
    float di = dinv[node];
    float sd = s2d[node];
    float es = s2s[node] + sd;
    es = (es >= 0.f) ? es : 0.2f * es;
    float psf = __expf(es);
    unsigned pvs = hp[(size_t)node * 16 + c];
    float accg = bf2f((unsigned short)pvs);
    float acca = bf2f((unsigned short)(pvs >> 16)) * psf;
    float lp = 0.f;
    int beg = rs[node], end = rs[node + 1];
    for (int j0 = beg; j0 < end; j0 += 16) {
        int cnt = min(16, end - j0);
        int sreg = 0;
        float pr = 0.f;
        if (c < cnt) {
            sreg = col[j0 + c];
            float e = s2s[sreg] + sd;
            e = (e >= 0.f) ? e : 0.2f * e;
            pr = __expf(e);
            lp += pr;
        }
        for (int e = 0; e < cnt; e += 4) {
            int si[4];
            float pi[4];
#pragma unroll
            for (int u = 0; u < 4; u++) {
                si[u] = __shfl(sreg, (e + u) & 15, 16);
                pi[u] = __shfl(pr, (e + u) & 15, 16);
            }
            unsigned hv[4];
#pragma unroll
            for (int u = 0; u < 4; u++) hv[u] = hp[(size_t)si[u] * 16 + c];
#pragma unroll
            for (int u = 0; u < 4; u++) {
                if (e + u < cnt) {
                    accg += bf2f((unsigned short)hv[u]);
                    acca += bf2f((unsigned short)(hv[u] >> 16)) * pi[u];
                }
            }
        }
    }
    for (int off = 8; off >= 1; off >>= 1) lp += __shfl_xor(lp, off, 16);
    float l = lp + psf;
    out[(size_t)node * 32 + c] = accg * di + bg2[c];
    out[(size_t)node * 32 + 16 + c] = acca / l + bga2[c];
}

// ---------------------------------------------------------------------------
// Launch
// ---------------------------------------------------------------------------
extern "C" void kernel_launch(void* const* d_in, const int* in_sizes, int n_in,
                              void* d_out, int out_size, void* d_ws, size_t ws_size,
                              hipStream_t stream) {
    const float* x      = (const float*)d_in[0];
    const int*   ei     = (const int*)d_in[1];
    const float* Wg1    = (const float*)d_in[2];
    const float* bg1    = (const float*)d_in[3];
    const float* Wg2    = (const float*)d_in[4];
    const float* bg2    = (const float*)d_in[5];
    const float* Wgat1  = (const float*)d_in[6];
    const float* a_src1 = (const float*)d_in[7];
    const float* a_dst1 = (const float*)d_in[8];
    const float* bgat1  = (const float*)d_in[9];
    const float* Wgat2  = (const float*)d_in[10];
    const float* a_src2 = (const float*)d_in[11];
    const float* a_dst2 = (const float*)d_in[12];
    const float* bgat2  = (const float*)d_in[13];
    float* out = (float*)d_out;

    const int* e_src = ei;
    const int* e_dst = ei + EE;

    char* wsb = (char*)d_ws;
    size_t o = 0;
    auto alloc = [&](size_t bytes) -> void* {
        void* p = wsb + o;
        o += (bytes + 255) & ~(size_t)255;
        return p;
    };
    float* dinv            = (float*)alloc(NN * 4);
    float* ssrc1           = (float*)alloc((size_t)NN * 16);
    float* sdst1           = (float*)alloc((size_t)NN * 16);
    unsigned short* h1b    = (unsigned short*)alloc((size_t)NN * HH * 2);
    unsigned short* xg1    = (unsigned short*)alloc((size_t)NN * HH * 2);
    unsigned short* hgb    = (unsigned short*)alloc((size_t)NN * 256 * 2);
    unsigned short* xgat1  = (unsigned short*)alloc((size_t)NN * 256 * 2);
    unsigned short* pairb  = (unsigned short*)alloc((size_t)NN * 16 * 4);  // interleaved h2|h2g
    float* s2src           = (float*)alloc(NN * 4);
    float* s2dst           = (float*)alloc(NN * 4);
    unsigned short* bhiC   = (unsigned short*)alloc((size_t)8 * NTT * 512 * 2);  // combined Wg1+Wgat1
    unsigned short* bloC   = (unsigned short*)alloc((size_t)8 * NTT * 512 * 2);
    unsigned short* bhiG2  = (unsigned short*)alloc(64 * 16 * 2);
    unsigned short* bloG2  = (unsigned short*)alloc(64 * 16 * 2);
    unsigned short* bhiA2  = (unsigned short*)alloc(256 * 16 * 2);
    unsigned short* bloA2  = (unsigned short*)alloc(256 * 16 * 2);
    int* cnt               = (int*)alloc(NN * 4);
    int* rowstart          = (int*)alloc((NN + 1) * 4);
    int* cursor            = (int*)alloc(NN * 4);
    int* colarr            = (int*)alloc((size_t)EE * 4);
    int* partial           = (int*)alloc(256 * 4);
    int* blockoff          = (int*)alloc(256 * 4);

    const int TB = 256;
    const int NB = (NN + 255) / 256;
    // CSR build + weight packing (one pack launch for all four weights)
    k_zero_int<<<(NN + TB - 1) / TB, TB, 0, stream>>>(cnt, NN);
    k_count<<<(EE + TB - 1) / TB, TB, 0, stream>>>(e_dst, cnt, EE);
    k_scan_a<<<NB, TB, 0, stream>>>(cnt, partial, NN);
    k_scan_b<<<1, TB, 0, stream>>>(partial, blockoff, rowstart + NN, NB);
    k_scan_c<<<NB, TB, 0, stream>>>(cnt, blockoff, rowstart, cursor, dinv, NN);
    k_fill<<<(EE + TB - 1) / TB, TB, 0, stream>>>(e_src, e_dst, cursor, colarr, EE);
    k_pack_all<<<(10880 + TB - 1) / TB, TB, 0, stream>>>(Wg1, Wgat1, Wg2, Wgat2,
                                                         bhiC, bloC, bhiG2, bloG2,
                                                         bhiA2, bloA2);

    const int GB = (NN + 63) / 64;    // 782
    const int G16 = (NN * 16) / 256;  // exact: 3125

    // Fused big GEMM: h1b (scaled) + hgb + s1 scores in ONE pass over x
    mfma_gemm_fused<<<GB, TB, 0, stream>>>(x, bhiC, bloC, h1b, hgb, dinv,
                                           a_src1, a_dst1, ssrc1, sdst1, NN);

    // GCN path
    gcn1_agg<<<(NN * 64) / TB, TB, 0, stream>>>(h1b, rowstart, colarr, dinv, bg1, xg1);
    mfma_n16<2, true, false, 0><<<GB, TB, 0, stream>>>(xg1, bhiG2, bloG2, pairb, dinv,
                                                       nullptr, nullptr, nullptr, nullptr, NN);

    // GAT path
    gat1_agg<<<NN / 4, TB, 0, stream>>>(hgb, rowstart, colarr, ssrc1, sdst1, bgat1, xgat1);
    mfma_n16<8, false, true, 1><<<GB, TB, 0, stream>>>(xgat1, bhiA2, bloA2, pairb, nullptr,
                                                       a_src2, a_dst2, s2src, s2dst, NN);

    // Fused GCN2+GAT2 aggregation -> d_out
    final_agg<<<G16, TB, 0, stream>>>((const unsigned*)pairb, rowstart, colarr, dinv,
                                      s2src, s2dst, bg2, bgat2, out);
}

// Round 12
// 358.148 us; speedup vs baseline: 1.0759x; 1.0759x over previous
//
#include <hip/hip_runtime.h>
#include <math.h>

#define NN     50000
#define FF     256
#define HH     64
#define NHEADS 4
#define EE     800000
#define OUTD   16

typedef __attribute__((ext_vector_type(8))) short short8;
typedef __attribute__((ext_vector_type(4))) float f32x4;

__device__ inline unsigned short f2bf(float f) {
    unsigned u = __builtin_bit_cast(unsigned, f);
    unsigned r = (u + 0x7fff + ((u >> 16) & 1)) >> 16;
    return (unsigned short)r;
}
__device__ inline float bf2f(unsigned short s) {
    unsigned u = ((unsigned)s) << 16;
    return __builtin_bit_cast(float, u);
}

// ---------------------------------------------------------------------------
// CSR build (3-phase hierarchical scan — round-4 lesson).
// ---------------------------------------------------------------------------
__global__ void k_zero_int(int* __restrict__ p, int n) {
    int i = blockIdx.x * blockDim.x + threadIdx.x;
    if (i < n) p[i] = 0;
}

__global__ void k_count(const int* __restrict__ dst, int* __restrict__ cnt, int e) {
    int i = blockIdx.x * blockDim.x + threadIdx.x;
    if (i < e) atomicAdd(&cnt[dst[i]], 1);
}

__global__ __launch_bounds__(256) void k_scan_a(const int* __restrict__ cnt,
                                                int* __restrict__ partial, int n) {
    int i = blockIdx.x * 256 + threadIdx.x;
    int v = (i < n) ? cnt[i] : 0;
#pragma unroll
    for (int off = 32; off >= 1; off >>= 1) v += __shfl_xor(v, off, 64);
    __shared__ int ws[4];
    int wave = threadIdx.x >> 6;
    if ((threadIdx.x & 63) == 0) ws[wave] = v;
    __syncthreads();
    if (threadIdx.x == 0) partial[blockIdx.x] = ws[0] + ws[1] + ws[2] + ws[3];
}

__global__ __launch_bounds__(256) void k_scan_b(const int* __restrict__ partial,
                                                int* __restrict__ blockoff,
                                                int* __restrict__ total_out, int nb) {
    __shared__ int arr[256];
    int tid = threadIdx.x;
    arr[tid] = (tid < nb) ? partial[tid] : 0;
    __syncthreads();
#pragma unroll
    for (int off = 1; off < 256; off <<= 1) {
        int v = arr[tid];
        int add = (tid >= off) ? arr[tid - off] : 0;
        __syncthreads();
        arr[tid] = v + add;
        __syncthreads();
    }
    if (tid < nb) blockoff[tid] = arr[tid] - partial[tid];
    if (tid == 0) *total_out = arr[255];
}

__global__ __launch_bounds__(256) void k_scan_c(const int* __restrict__ cnt,
                                                const int* __restrict__ blockoff,
                                                int* __restrict__ row_start,
                                                int* __restrict__ cursor,
                                                float* __restrict__ dinv, int n) {
    __shared__ int arr[256];
    int tid = threadIdx.x;
    int i = blockIdx.x * 256 + tid;
    int c = (i < n) ? cnt[i] : 0;
    arr[tid] = c;
    __syncthreads();
#pragma unroll
    for (int off = 1; off < 256; off <<= 1) {
        int v = arr[tid];
        int add = (tid >= off) ? arr[tid - off] : 0;
        __syncthreads();
        arr[tid] = v + add;
        __syncthreads();
    }
    if (i < n) {
        int excl = arr[tid] - c + blockoff[blockIdx.x];
        row_start[i] = excl;
        cursor[i] = excl;
        dinv[i] = rsqrtf((float)(c + 1));
    }
}

__global__ void k_fill(const int* __restrict__ src, const int* __restrict__ dst,
                       int* __restrict__ cursor, int* __restrict__ col, int e) {
    int i = blockIdx.x * blockDim.x + threadIdx.x;
    if (i < e) {
        int d = dst[i];
        int pos = atomicAdd(&cursor[d], 1);
        col[pos] = src[i];
    }
}

// ---------------------------------------------------------------------------
// Weight packing, single launch. For the big fused GEMM only Bhi is packed
// (round-12: big GEMM keeps A-split compensation, drops A*Blo — halves the
// LDS stage). Small N=16 GEMMs keep full hi/lo.
// ---------------------------------------------------------------------------
__device__ inline void pack_one(const float* __restrict__ W,
                                unsigned short* __restrict__ bhi,
                                unsigned short* __restrict__ blo,
                                int t_, int NT, int NTOT, int TOFF, int SRC_NC) {
    int lane = t_ & 63;
    int tile = (t_ >> 6) % NT;
    int kb = (t_ >> 6) / NT;
    int q = lane >> 4, c = lane & 15;
    size_t off = ((size_t)(kb * NTOT + TOFF + tile) * 64 + lane) * 8;
#pragma unroll
    for (int j = 0; j < 8; j++) {
        float w = W[(size_t)(kb * 32 + q * 8 + j) * SRC_NC + tile * 16 + c];
        unsigned short h = f2bf(w);
        bhi[off + j] = h;
        if (blo) blo[off + j] = f2bf(w - bf2f(h));
    }
}

#define NTT 20
__global__ __launch_bounds__(256) void k_pack_all(const float* __restrict__ Wg1,
                                                  const float* __restrict__ Wgat1,
                                                  const float* __restrict__ Wg2,
                                                  const float* __restrict__ Wgat2,
                                                  unsigned short* __restrict__ bhiC,
                                                  unsigned short* __restrict__ bhiG2,
                                                  unsigned short* __restrict__ bloG2,
                                                  unsigned short* __restrict__ bhiA2,
                                                  unsigned short* __restrict__ bloA2) {
    int t = blockIdx.x * 256 + threadIdx.x;
    if (t < 2048)        pack_one(Wg1,   bhiC,  nullptr, t,         4,  NTT, 0, 64);
    else if (t < 10240)  pack_one(Wgat1, bhiC,  nullptr, t - 2048,  16, NTT, 4, 256);
    else if (t < 10368)  pack_one(Wg2,   bhiG2, bloG2,   t - 10240, 1,  1,   0, 16);
    else if (t < 10880)  pack_one(Wgat2, bhiA2, bloA2,   t - 10368, 1,  1,   0, 16);
}

// ---------------------------------------------------------------------------
// FUSED big GEMM: one pass over x -> h1 (4 tiles, dinv-scaled) + hgat
// (16 tiles) + fused s1 scores. A split hi/lo (2 MFMAs/tile), B hi only —
// B-rounding error ~1.6e-3 std on h, same order as the bf16 storage
// rounding already present. Manual LDS staging (round-11: async
// global_load_lds REGRESSED 66.7->88 µs on this stage-heavy shape — do not
// reintroduce). Stage is now 20 KB/kb.
// ---------------------------------------------------------------------------
__global__ __launch_bounds__(256) void mfma_gemm_fused(const float* __restrict__ A,
                                                       const unsigned short* __restrict__ Bhi,
                                                       unsigned short* __restrict__ Ch1,
                                                       unsigned short* __restrict__ Chg,
                                                       const float* __restrict__ dinv,
                                                       const float* __restrict__ a_s,
                                                       const float* __restrict__ a_d,
                                                       float* __restrict__ ssrc,
                                                       float* __restrict__ sdst,
                                                       int M) {
    const int K = 256;
    __shared__ short8 bsh[NTT * 64];   // 20 KB
    int tid = threadIdx.x;
    int w = tid >> 6, lane = tid & 63, q = lane >> 4, c = lane & 15;
    int row_base = blockIdx.x * 64 + w * 16;
    int ar = min(row_base + c, M - 1);
    const float* ap = A + (size_t)ar * K + q * 8;

    f32x4 acc[NTT];
#pragma unroll
    for (int t = 0; t < NTT; t++) acc[t] = (f32x4){0.f, 0.f, 0.f, 0.f};

    for (int kb = 0; kb < 8; kb++) {
        float av[8];
        *(float4*)(av)     = *(const float4*)(ap + kb * 32);
        *(float4*)(av + 4) = *(const float4*)(ap + kb * 32 + 4);
        short8 ahi, alo;
#pragma unroll
        for (int j = 0; j < 8; j++) {
            unsigned short h = f2bf(av[j]);
            ahi[j] = (short)h;
            alo[j] = (short)f2bf(av[j] - bf2f(h));
        }
        const short8* gh = (const short8*)(Bhi + (size_t)kb * NTT * 512);
        __syncthreads();  // readers of previous kb done
        for (int i = tid; i < NTT * 64; i += 256) bsh[i] = gh[i];
        __syncthreads();
#pragma unroll
        for (int t = 0; t < NTT; t++) {
            short8 bhi = bsh[t * 64 + lane];
            acc[t] = __builtin_amdgcn_mfma_f32_16x16x32_bf16(ahi, bhi, acc[t], 0, 0, 0);
            acc[t] = __builtin_amdgcn_mfma_f32_16x16x32_bf16(alo, bhi, acc[t], 0, 0, 0);
        }
    }

    // s1 scores over the 16 GAT tiles (tiles 4..19; head = (t-4)>>2)
#pragma unroll
    for (int i = 0; i < 4; i++) {
        int r = row_base + q * 4 + i;
        float ss[4] = {0.f, 0.f, 0.f, 0.f};
        float sd[4] = {0.f, 0.f, 0.f, 0.f};
#pragma unroll
        for (int t = 0; t < 16; t++) {
            float v = acc[t + 4][i];
            ss[t >> 2] += v * a_s[t * 16 + c];
            sd[t >> 2] += v * a_d[t * 16 + c];
        }
#pragma unroll
        for (int h = 0; h < 4; h++) {
#pragma unroll
            for (int off = 1; off <= 8; off <<= 1) {
                ss[h] += __shfl_xor(ss[h], off, 16);
                sd[h] += __shfl_xor(sd[h], off, 16);
            }
        }
        if (c == i && r < M) {
            *(float4*)(ssrc + (size_t)r * 4) = make_float4(ss[0], ss[1], ss[2], ss[3]);
            *(float4*)(sdst + (size_t)r * 4) = make_float4(sd[0], sd[1], sd[2], sd[3]);
        }
    }

#pragma unroll
    for (int i = 0; i < 4; i++) {
        int r = row_base + q * 4 + i;
        if (r < M) {
            float sc = dinv[r];
#pragma unroll
            for (int t = 0; t < 4; t++)
                Ch1[(size_t)r * 64 + t * 16 + c] = f2bf(acc[t][i] * sc);
#pragma unroll
            for (int t = 0; t < 16; t++)
                Chg[(size_t)r * 256 + t * 16 + c] = f2bf(acc[t + 4][i]);
        }
    }
}

// ---------------------------------------------------------------------------
// MFMA GEMM with N=16, A exact bf16 (K=KB*32). W2 split hi/lo -> 2 MFMAs
// (kept fully compensated — feeds the output directly). Output bf16 into
// the INTERLEAVED pair buffer at [(r*16+c)*2 + OFS].
// ---------------------------------------------------------------------------
template <int KB, bool SCALE, bool SC2, int OFS>
__global__ __launch_bounds__(256) void mfma_n16(const unsigned short* __restrict__ A,
                                                const unsigned short* __restrict__ Bhi,
                                                const unsigned short* __restrict__ Blo,
                                                unsigned short* __restrict__ Cbf,
                                                const float* __restrict__ rowscale,
                                                const float* __restrict__ a_s2,
                                                const float* __restrict__ a_d2,
                                                float* __restrict__ s2s,
                                                float* __restrict__ s2d, int M) {
    const int K = KB * 32;
    int tid = threadIdx.x;
    int w = tid >> 6, lane = tid & 63, q = lane >> 4, c = lane & 15;
    int row_base = blockIdx.x * 64 + w * 16;
    int ar = min(row_base + c, M - 1);
    const unsigned short* ap = A + (size_t)ar * K + q * 8;
    f32x4 acc = (f32x4){0.f, 0.f, 0.f, 0.f};
#pragma unroll
    for (int kb = 0; kb < KB; kb++) {
        short8 av = *(const short8*)(ap + kb * 32);
        size_t bo = ((size_t)kb * 64 + lane) * 8;
        short8 bh = *(const short8*)(Bhi + bo);
        short8 bl = *(const short8*)(Blo + bo);
        acc = __builtin_amdgcn_mfma_f32_16x16x32_bf16(av, bh, acc, 0, 0, 0);
        acc = __builtin_amdgcn_mfma_f32_16x16x32_bf16(av, bl, acc, 0, 0, 0);
    }
    if (SC2) {
#pragma unroll
        for (int i = 0; i < 4; i++) {
            float ps = acc[i] * a_s2[c];
            float pd = acc[i] * a_d2[c];
#pragma unroll
            for (int off = 1; off <= 8; off <<= 1) {
                ps += __shfl_xor(ps, off, 16);
                pd += __shfl_xor(pd, off, 16);
            }
            int r = row_base + q * 4 + i;
            if (c == i && r < M) {
                s2s[r] = ps;
                s2d[r] = pd;
            }
        }
    }
#pragma unroll
    for (int i = 0; i < 4; i++) {
        int r = row_base + q * 4 + i;
        if (r < M) {
            float sc = SCALE ? rowscale[r] : 1.0f;
            Cbf[((size_t)r * 16 + c) * 2 + OFS] = f2bf(acc[i] * sc);
        }
    }
}

// ---------------------------------------------------------------------------
// GCN1 aggregation, h1 bf16, pre-scaled by dinv; out bf16. 16 edges/iter.
// ---------------------------------------------------------------------------
__global__ __launch_bounds__(256) void gcn1_agg(const unsigned short* __restrict__ h,
                                                const int* __restrict__ rs,
                                                const int* __restrict__ col,
                                                const float* __restrict__ dinv,
                                                const float* __restrict__ b,
                                                unsigned short* __restrict__ out) {
    int wid = (blockIdx.x * 256 + threadIdx.x) >> 6;
    int lane = threadIdx.x & 63;
    if (wid >= NN) return;
    int g = lane >> 4;
    int cidx = (lane & 15) * 4;
    float di = dinv[wid];
    int beg = rs[wid], end = rs[wid + 1];
    float4 acc = make_float4(0.f, 0.f, 0.f, 0.f);

    for (int j0 = beg; j0 < end; j0 += 64) {
        int cnt = min(64, end - j0);
        int sreg = 0;
        if (lane < cnt) sreg = col[j0 + lane];
        for (int e = 0; e < cnt; e += 16) {
            int m0 = e + g, m1 = e + g + 4, m2 = e + g + 8, m3 = e + g + 12;
            int s0 = __shfl(sreg, m0, 64);   // unconditional (round-2 lesson)
            int s1 = __shfl(sreg, m1, 64);
            int s2 = __shfl(sreg, m2, 64);
            int s3 = __shfl(sreg, m3, 64);
            ushort4 v0 = make_ushort4(0, 0, 0, 0), v1 = make_ushort4(0, 0, 0, 0);
            ushort4 v2 = make_ushort4(0, 0, 0, 0), v3 = make_ushort4(0, 0, 0, 0);
            if (m0 < cnt) v0 = *(const ushort4*)(h + (size_t)s0 * HH + cidx);
            if (m1 < cnt) v1 = *(const ushort4*)(h + (size_t)s1 * HH + cidx);
            if (m2 < cnt) v2 = *(const ushort4*)(h + (size_t)s2 * HH + cidx);
            if (m3 < cnt) v3 = *(const ushort4*)(h + (size_t)s3 * HH + cidx);
            acc.x += (bf2f(v0.x) + bf2f(v1.x)) + (bf2f(v2.x) + bf2f(v3.x));
            acc.y += (bf2f(v0.y) + bf2f(v1.y)) + (bf2f(v2.y) + bf2f(v3.y));
            acc.z += (bf2f(v0.z) + bf2f(v1.z)) + (bf2f(v2.z) + bf2f(v3.z));
            acc.w += (bf2f(v0.w) + bf2f(v1.w)) + (bf2f(v2.w) + bf2f(v3.w));
        }
    }
#pragma unroll
    for (int off = 16; off <= 32; off <<= 1) {
        acc.x += __shfl_xor(acc.x, off, 64);
        acc.y += __shfl_xor(acc.y, off, 64);
        acc.z += __shfl_xor(acc.z, off, 64);
        acc.w += __shfl_xor(acc.w, off, 64);
    }
    if (g == 0) {
        ushort4 sv = *(const ushort4*)(h + (size_t)wid * HH + cidx);
        float4 bv = *(const float4*)(b + cidx);
        ushort4 o;
        o.x = f2bf(fmaxf((acc.x + bf2f(sv.x)) * di + bv.x, 0.f));
        o.y = f2bf(fmaxf((acc.y + bf2f(sv.y)) * di + bv.y, 0.f));
        o.z = f2bf(fmaxf((acc.z + bf2f(sv.z)) * di + bv.z, 0.f));
        o.w = f2bf(fmaxf((acc.w + bf2f(sv.w)) * di + bv.w, 0.f));
        *(ushort4*)(out + (size_t)wid * HH + cidx) = o;
    }
}

// ---------------------------------------------------------------------------
// GAT1 aggregation: LDS-staged p/src; 4-edge unrolled gather. At its
// fabric-ceiling floor (~3.6 TB/s FETCH-side) — kept unchanged (control).
// ---------------------------------------------------------------------------
__global__ __launch_bounds__(256) void gat1_agg(const unsigned short* __restrict__ hg,
                                                const int* __restrict__ rs,
                                                const int* __restrict__ col,
                                                const float* __restrict__ ssrc,
                                                const float* __restrict__ sdst,
                                                const float* __restrict__ b,
                                                unsigned short* __restrict__ out) {
    __shared__ int s_lds[4][64];
    __shared__ float p_lds[4][64 * 4];
    int tid = threadIdx.x;
    int w = tid >> 6, lane = tid & 63;
    int wid = blockIdx.x * 4 + w;       // grid exact: 12500*4 = NN
    int hh = lane >> 4;
    int* sl = s_lds[w];
    float* pl = p_lds[w];

    float4 sd4 = *(const float4*)(sdst + (size_t)wid * 4);
    float sdv[4] = {sd4.x, sd4.y, sd4.z, sd4.w};
    float4 sf4 = *(const float4*)(ssrc + (size_t)wid * 4);
    float sfv[4] = {sf4.x, sf4.y, sf4.z, sf4.w};
    float psf[4];
#pragma unroll
    for (int h = 0; h < 4; h++) {
        float e = sfv[h] + sdv[h];
        e = (e >= 0.f) ? e : 0.2f * e;
        psf[h] = __expf(e);
    }
    float pse = (hh & 2) ? ((hh & 1) ? psf[3] : psf[2]) : ((hh & 1) ? psf[1] : psf[0]);
    const unsigned short* hbase = hg + lane * 4;
    ushort4 hvs = *(const ushort4*)(hbase + (size_t)wid * 256);
    float4 acc;
    acc.x = bf2f(hvs.x) * pse; acc.y = bf2f(hvs.y) * pse;
    acc.z = bf2f(hvs.z) * pse; acc.w = bf2f(hvs.w) * pse;

    float lsum[4] = {0.f, 0.f, 0.f, 0.f};
    int beg = rs[wid], end = rs[wid + 1];
    for (int j0 = beg; j0 < end; j0 += 64) {
        int cnt = min(64, end - j0);
        if (lane < cnt) {
            int sreg = col[j0 + lane];
            float4 sv = *(const float4*)(ssrc + (size_t)sreg * 4);
            float svv[4] = {sv.x, sv.y, sv.z, sv.w};
            float pv[4];
#pragma unroll
            for (int h = 0; h < 4; h++) {
                float e = svv[h] + sdv[h];
                e = (e >= 0.f) ? e : 0.2f * e;
                pv[h] = __expf(e);
                lsum[h] += pv[h];
            }
            sl[lane] = sreg;
            *(float4*)&pl[lane * 4] = make_float4(pv[0], pv[1], pv[2], pv[3]);
        }
        int e = 0;
        for (; e + 4 <= cnt; e += 4) {
            int s0 = sl[e], s1 = sl[e + 1], s2 = sl[e + 2], s3 = sl[e + 3];
            float p0 = pl[e * 4 + hh], p1 = pl[(e + 1) * 4 + hh];
            float p2 = pl[(e + 2) * 4 + hh], p3 = pl[(e + 3) * 4 + hh];
            ushort4 h0 = *(const ushort4*)(hbase + (size_t)s0 * 256);
            ushort4 h1 = *(const ushort4*)(hbase + (size_t)s1 * 256);
            ushort4 h2 = *(const ushort4*)(hbase + (size_t)s2 * 256);
            ushort4 h3 = *(const ushort4*)(hbase + (size_t)s3 * 256);
            acc.x += bf2f(h0.x) * p0; acc.y += bf2f(h0.y) * p0;
            acc.z += bf2f(h0.z) * p0; acc.w += bf2f(h0.w) * p0;
            acc.x += bf2f(h1.x) * p1; acc.y += bf2f(h1.y) * p1;
            acc.z += bf2f(h1.z) * p1; acc.w += bf2f(h1.w) * p1;
            acc.x += bf2f(h2.x) * p2; acc.y += bf2f(h2.y) * p2;
            acc.z += bf2f(h2.z) * p2; acc.w += bf2f(h2.w) * p2;
            acc.x += bf2f(h3.x) * p3; acc.y += bf2f(h3.y) * p3;
            acc.z += bf2f(h3.z) * p3; acc.w += bf2f(h3.w) * p3;
        }
        for (; e < cnt; e++) {
            int s = sl[e];
            float p = pl[e * 4 + hh];
            ushort4 hv = *(const ushort4*)(hbase + (size_t)s * 256);
            acc.x += bf2f(hv.x) * p; acc.y += bf2f(hv.y) * p;
            acc.z += bf2f(hv.z) * p; acc.w += bf2f(hv.w) * p;
        }
    }
#pragma unroll
    for (int h = 0; h < 4; h++) {
        float v = lsum[h];
        for (int off = 32; off >= 1; off >>= 1) v += __shfl_xor(v, off, 64);
        lsum[h] = v + psf[h];
    }
    float lt = (hh & 2) ? ((hh & 1) ? lsum[3] : lsum[2]) : ((hh & 1) ? lsum[1] : lsum[0]);
    float li = 1.0f / lt;
    float4 bv = *(const float4*)(b + lane * 4);
    ushort4 o;
    o.x = f2bf(fmaxf(acc.x * li + bv.x, 0.f));
    o.y = f2bf(fmaxf(acc.y * li + bv.y, 0.f));
    o.z = f2bf(fmaxf(acc.z * li + bv.z, 0.f));
    o.w = f2bf(fmaxf(acc.w * li + bv.w, 0.f));
    *(ushort4*)(out + (size_t)wid * 256 + lane * 4) = o;
}

// ---------------------------------------------------------------------------
// Final aggregation: fused GCN2 + GAT2 over the interleaved pair buffer.
// ---------------------------------------------------------------------------
__global__ __launch_bounds__(256) void final_agg(const unsigned* __restrict__ hp,
                                                 const int* __restrict__ rs,
                                                 const int* __restrict__ col,
                                                 const float* __restrict__ dinv,
                                                 const float* __restrict__ s2s,
                                                 const float* __restrict__ s2d,
                                                 const float* __restrict__ bg2,
                                                 const float* __restrict__ bga2,
                                                 float* __restrict__ out) {
    int t = blockIdx.x * 256 + threadIdx.x;
    int node = t >> 4;
    int c = t & 15;
    float di = dinv[node];
    float sd = s2d[node];
    float es = s2s[node] + sd;
    es = (es >= 0.f) ? es : 0.2f * es;
    float psf = __expf(es);
    unsigned pvs = hp[(size_t)node * 16 + c];
    float accg = bf2f((unsigned short)pvs);
    float acca = bf2f((unsigned short)(pvs >> 16)) * psf;
    float lp = 0.f;
    int beg = rs[node], end = rs[node + 1];
    for (int j0 = beg; j0 < end; j0 += 16) {
        int cnt = min(16, end - j0);
        int sreg = 0;
        float pr = 0.f;
        if (c < cnt) {
            sreg = col[j0 + c];
            float e = s2s[sreg] + sd;
            e = (e >= 0.f) ? e : 0.2f * e;
            pr = __expf(e);
            lp += pr;
        }
        for (int e = 0; e < cnt; e += 4) {
            int si[4];
            float pi[4];
#pragma unroll
            for (int u = 0; u < 4; u++) {
                si[u] = __shfl(sreg, (e + u) & 15, 16);
                pi[u] = __shfl(pr, (e + u) & 15, 16);
            }
            unsigned hv[4];
#pragma unroll
            for (int u = 0; u < 4; u++) hv[u] = hp[(size_t)si[u] * 16 + c];
#pragma unroll
            for (int u = 0; u < 4; u++) {
                if (e + u < cnt) {
                    accg += bf2f((unsigned short)hv[u]);
                    acca += bf2f((unsigned short)(hv[u] >> 16)) * pi[u];
                }
            }
        }
    }
    for (int off = 8; off >= 1; off >>= 1) lp += __shfl_xor(lp, off, 16);
    float l = lp + psf;
    out[(size_t)node * 32 + c] = accg * di + bg2[c];
    out[(size_t)node * 32 + 16 + c] = acca / l + bga2[c];
}

// ---------------------------------------------------------------------------
// Launch
// ---------------------------------------------------------------------------
extern "C" void kernel_launch(void* const* d_in, const int* in_sizes, int n_in,
                              void* d_out, int out_size, void* d_ws, size_t ws_size,
                              hipStream_t stream) {
    const float* x      = (const float*)d_in[0];
    const int*   ei     = (const int*)d_in[1];
    const float* Wg1    = (const float*)d_in[2];
    const float* bg1    = (const float*)d_in[3];
    const float* Wg2    = (const float*)d_in[4];
    const float* bg2    = (const float*)d_in[5];
    const float* Wgat1  = (const float*)d_in[6];
    const float* a_src1 = (const float*)d_in[7];
    const float* a_dst1 = (const float*)d_in[8];
    const float* bgat1  = (const float*)d_in[9];
    const float* Wgat2  = (const float*)d_in[10];
    const float* a_src2 = (const float*)d_in[11];
    const float* a_dst2 = (const float*)d_in[12];
    const float* bgat2  = (const float*)d_in[13];
    float* out = (float*)d_out;

    const int* e_src = ei;
    const int* e_dst = ei + EE;

    char* wsb = (char*)d_ws;
    size_t o = 0;
    auto alloc = [&](size_t bytes) -> void* {
        void* p = wsb + o;
        o += (bytes + 255) & ~(size_t)255;
        return p;
    };
    float* dinv            = (float*)alloc(NN * 4);
    float* ssrc1           = (float*)alloc((size_t)NN * 16);
    float* sdst1           = (float*)alloc((size_t)NN * 16);
    unsigned short* h1b    = (unsigned short*)alloc((size_t)NN * HH * 2);
    unsigned short* xg1    = (unsigned short*)alloc((size_t)NN * HH * 2);
    unsigned short* hgb    = (unsigned short*)alloc((size_t)NN * 256 * 2);
    unsigned short* xgat1  = (unsigned short*)alloc((size_t)NN * 256 * 2);
    unsigned short* pairb  = (unsigned short*)alloc((size_t)NN * 16 * 4);  // interleaved h2|h2g
    float* s2src           = (float*)alloc(NN * 4);
    float* s2dst           = (float*)alloc(NN * 4);
    unsigned short* bhiC   = (unsigned short*)alloc((size_t)8 * NTT * 512 * 2);  // combined Wg1+Wgat1 (hi only)
    unsigned short* bhiG2  = (unsigned short*)alloc(64 * 16 * 2);
    unsigned short* bloG2  = (unsigned short*)alloc(64 * 16 * 2);
    unsigned short* bhiA2  = (unsigned short*)alloc(256 * 16 * 2);
    unsigned short* bloA2  = (unsigned short*)alloc(256 * 16 * 2);
    int* cnt               = (int*)alloc(NN * 4);
    int* rowstart          = (int*)alloc((NN + 1) * 4);
    int* cursor            = (int*)alloc(NN * 4);
    int* colarr            = (int*)alloc((size_t)EE * 4);
    int* partial           = (int*)alloc(256 * 4);
    int* blockoff          = (int*)alloc(256 * 4);

    const int TB = 256;
    const int NB = (NN + 255) / 256;
    // CSR build + weight packing (one pack launch)
    k_zero_int<<<(NN + TB - 1) / TB, TB, 0, stream>>>(cnt, NN);
    k_count<<<(EE + TB - 1) / TB, TB, 0, stream>>>(e_dst, cnt, EE);
    k_scan_a<<<NB, TB, 0, stream>>>(cnt, partial, NN);
    k_scan_b<<<1, TB, 0, stream>>>(partial, blockoff, rowstart + NN, NB);
    k_scan_c<<<NB, TB, 0, stream>>>(cnt, blockoff, rowstart, cursor, dinv, NN);
    k_fill<<<(EE + TB - 1) / TB, TB, 0, stream>>>(e_src, e_dst, cursor, colarr, EE);
    k_pack_all<<<(10880 + TB - 1) / TB, TB, 0, stream>>>(Wg1, Wgat1, Wg2, Wgat2,
                                                         bhiC, bhiG2, bloG2,
                                                         bhiA2, bloA2);

    const int GB = (NN + 63) / 64;    // 782
    const int G16 = (NN * 16) / 256;  // exact: 3125

    // Fused big GEMM: h1b (scaled) + hgb + s1 scores in ONE pass over x
    mfma_gemm_fused<<<GB, TB, 0, stream>>>(x, bhiC, h1b, hgb, dinv,
                                           a_src1, a_dst1, ssrc1, sdst1, NN);

    // GCN path
    gcn1_agg<<<(NN * 64) / TB, TB, 0, stream>>>(h1b, rowstart, colarr, dinv, bg1, xg1);
    mfma_n16<2, true, false, 0><<<GB, TB, 0, stream>>>(xg1, bhiG2, bloG2, pairb, dinv,
                                                       nullptr, nullptr, nullptr, nullptr, NN);

    // GAT path
    gat1_agg<<<NN / 4, TB, 0, stream>>>(hgb, rowstart, colarr, ssrc1, sdst1, bgat1, xgat1);
    mfma_n16<8, false, true, 1><<<GB, TB, 0, stream>>>(xgat1, bhiA2, bloA2, pairb, nullptr,
                                                       a_src2, a_dst2, s2src, s2dst, NN);

    // Fused GCN2+GAT2 aggregation -> d_out
    final_agg<<<G16, TB, 0, stream>>>((const unsigned*)pairb, rowstart, colarr, dinv,
                                      s2src, s2dst, bg2, bgat2, out);
}

// Round 13
// 355.200 us; speedup vs baseline: 1.0849x; 1.0083x over previous
//
#include <hip/hip_runtime.h>
#include <math.h>

#define NN     50000
#define FF     256
#define HH     64
#define NHEADS 4
#define EE     800000
#define OUTD   16

typedef __attribute__((ext_vector_type(8))) short short8;
typedef __attribute__((ext_vector_type(4))) float f32x4;

__device__ inline unsigned short f2bf(float f) {
    unsigned u = __builtin_bit_cast(unsigned, f);
    unsigned r = (u + 0x7fff + ((u >> 16) & 1)) >> 16;
    return (unsigned short)r;
}
__device__ inline float bf2f(unsigned short s) {
    unsigned u = ((unsigned)s) << 16;
    return __builtin_bit_cast(float, u);
}

// ---------------------------------------------------------------------------
// CSR build (3-phase hierarchical scan — round-4 lesson).
// ---------------------------------------------------------------------------
__global__ void k_zero_int(int* __restrict__ p, int n) {
    int i = blockIdx.x * blockDim.x + threadIdx.x;
    if (i < n) p[i] = 0;
}

__global__ void k_count(const int* __restrict__ dst, int* __restrict__ cnt, int e) {
    int i = blockIdx.x * blockDim.x + threadIdx.x;
    if (i < e) atomicAdd(&cnt[dst[i]], 1);
}

__global__ __launch_bounds__(256) void k_scan_a(const int* __restrict__ cnt,
                                                int* __restrict__ partial, int n) {
    int i = blockIdx.x * 256 + threadIdx.x;
    int v = (i < n) ? cnt[i] : 0;
#pragma unroll
    for (int off = 32; off >= 1; off >>= 1) v += __shfl_xor(v, off, 64);
    __shared__ int ws[4];
    int wave = threadIdx.x >> 6;
    if ((threadIdx.x & 63) == 0) ws[wave] = v;
    __syncthreads();
    if (threadIdx.x == 0) partial[blockIdx.x] = ws[0] + ws[1] + ws[2] + ws[3];
}

__global__ __launch_bounds__(256) void k_scan_b(const int* __restrict__ partial,
                                                int* __restrict__ blockoff,
                                                int* __restrict__ total_out, int nb) {
    __shared__ int arr[256];
    int tid = threadIdx.x;
    arr[tid] = (tid < nb) ? partial[tid] : 0;
    __syncthreads();
#pragma unroll
    for (int off = 1; off < 256; off <<= 1) {
        int v = arr[tid];
        int add = (tid >= off) ? arr[tid - off] : 0;
        __syncthreads();
        arr[tid] = v + add;
        __syncthreads();
    }
    if (tid < nb) blockoff[tid] = arr[tid] - partial[tid];
    if (tid == 0) *total_out = arr[255];
}

__global__ __launch_bounds__(256) void k_scan_c(const int* __restrict__ cnt,
                                                const int* __restrict__ blockoff,
                                                int* __restrict__ row_start,
                                                int* __restrict__ cursor,
                                                float* __restrict__ dinv, int n) {
    __shared__ int arr[256];
    int tid = threadIdx.x;
    int i = blockIdx.x * 256 + tid;
    int c = (i < n) ? cnt[i] : 0;
    arr[tid] = c;
    __syncthreads();
#pragma unroll
    for (int off = 1; off < 256; off <<= 1) {
        int v = arr[tid];
        int add = (tid >= off) ? arr[tid - off] : 0;
        __syncthreads();
        arr[tid] = v + add;
        __syncthreads();
    }
    if (i < n) {
        int excl = arr[tid] - c + blockoff[blockIdx.x];
        row_start[i] = excl;
        cursor[i] = excl;
        dinv[i] = rsqrtf((float)(c + 1));
    }
}

__global__ void k_fill(const int* __restrict__ src, const int* __restrict__ dst,
                       int* __restrict__ cursor, int* __restrict__ col, int e) {
    int i = blockIdx.x * blockDim.x + threadIdx.x;
    if (i < e) {
        int d = dst[i];
        int pos = atomicAdd(&cursor[d], 1);
        col[pos] = src[i];
    }
}

// ---------------------------------------------------------------------------
// Weight packing, single launch. Big fused GEMM: Bhi only (round-12 win —
// error stayed storage-floor-dominated). Small N=16 GEMMs: full hi/lo.
// ---------------------------------------------------------------------------
__device__ inline void pack_one(const float* __restrict__ W,
                                unsigned short* __restrict__ bhi,
                                unsigned short* __restrict__ blo,
                                int t_, int NT, int NTOT, int TOFF, int SRC_NC) {
    int lane = t_ & 63;
    int tile = (t_ >> 6) % NT;
    int kb = (t_ >> 6) / NT;
    int q = lane >> 4, c = lane & 15;
    size_t off = ((size_t)(kb * NTOT + TOFF + tile) * 64 + lane) * 8;
#pragma unroll
    for (int j = 0; j < 8; j++) {
        float w = W[(size_t)(kb * 32 + q * 8 + j) * SRC_NC + tile * 16 + c];
        unsigned short h = f2bf(w);
        bhi[off + j] = h;
        if (blo) blo[off + j] = f2bf(w - bf2f(h));
    }
}

#define NTT 20
__global__ __launch_bounds__(256) void k_pack_all(const float* __restrict__ Wg1,
                                                  const float* __restrict__ Wgat1,
                                                  const float* __restrict__ Wg2,
                                                  const float* __restrict__ Wgat2,
                                                  unsigned short* __restrict__ bhiC,
                                                  unsigned short* __restrict__ bhiG2,
                                                  unsigned short* __restrict__ bloG2,
                                                  unsigned short* __restrict__ bhiA2,
                                                  unsigned short* __restrict__ bloA2) {
    int t = blockIdx.x * 256 + threadIdx.x;
    if (t < 2048)        pack_one(Wg1,   bhiC,  nullptr, t,         4,  NTT, 0, 64);
    else if (t < 10240)  pack_one(Wgat1, bhiC,  nullptr, t - 2048,  16, NTT, 4, 256);
    else if (t < 10368)  pack_one(Wg2,   bhiG2, bloG2,   t - 10240, 1,  1,   0, 16);
    else if (t < 10880)  pack_one(Wgat2, bhiA2, bloA2,   t - 10368, 1,  1,   0, 16);
}

// ---------------------------------------------------------------------------
// FUSED big GEMM: one pass over x -> h1 (4 tiles, dinv-scaled) + hgat
// (16 tiles) + fused s1 scores. A split hi/lo (2 MFMAs/tile), B hi only.
// Round-13: NO LDS staging, NO __syncthreads — B (160 KB) is L2-resident,
// each wave reads its fragments directly from global. Rounds 10-12 showed
// the per-kb barrier pair pinned MfmaUtil at 10-16% with all pipes idle;
// barrier-free waves let the compiler's vmcnt pipelining hide the ~200 cyc
// L2 hits. (Round-11 lesson also holds: no async global_load_lds here.)
// ---------------------------------------------------------------------------
__global__ __launch_bounds__(256) void mfma_gemm_fused(const float* __restrict__ A,
                                                       const unsigned short* __restrict__ Bhi,
                                                       unsigned short* __restrict__ Ch1,
                                                       unsigned short* __restrict__ Chg,
                                                       const float* __restrict__ dinv,
                                                       const float* __restrict__ a_s,
                                                       const float* __restrict__ a_d,
                                                       float* __restrict__ ssrc,
                                                       float* __restrict__ sdst,
                                                       int M) {
    const int K = 256;
    int tid = threadIdx.x;
    int w = tid >> 6, lane = tid & 63, q = lane >> 4, c = lane & 15;
    int row_base = blockIdx.x * 64 + w * 16;
    int ar = min(row_base + c, M - 1);
    const float* ap = A + (size_t)ar * K + q * 8;
    const short8* bp = (const short8*)Bhi + lane;

    f32x4 acc[NTT];
#pragma unroll
    for (int t = 0; t < NTT; t++) acc[t] = (f32x4){0.f, 0.f, 0.f, 0.f};

    for (int kb = 0; kb < 8; kb++) {
        float av[8];
        *(float4*)(av)     = *(const float4*)(ap + kb * 32);
        *(float4*)(av + 4) = *(const float4*)(ap + kb * 32 + 4);
        short8 ahi, alo;
#pragma unroll
        for (int j = 0; j < 8; j++) {
            unsigned short h = f2bf(av[j]);
            ahi[j] = (short)h;
            alo[j] = (short)f2bf(av[j] - bf2f(h));
        }
#pragma unroll
        for (int t = 0; t < NTT; t++) {
            short8 bhi = bp[(size_t)(kb * NTT + t) * 64];
            acc[t] = __builtin_amdgcn_mfma_f32_16x16x32_bf16(ahi, bhi, acc[t], 0, 0, 0);
            acc[t] = __builtin_amdgcn_mfma_f32_16x16x32_bf16(alo, bhi, acc[t], 0, 0, 0);
        }
    }

    // s1 scores over the 16 GAT tiles (tiles 4..19; head = (t-4)>>2)
#pragma unroll
    for (int i = 0; i < 4; i++) {
        int r = row_base + q * 4 + i;
        float ss[4] = {0.f, 0.f, 0.f, 0.f};
        float sd[4] = {0.f, 0.f, 0.f, 0.f};
#pragma unroll
        for (int t = 0; t < 16; t++) {
            float v = acc[t + 4][i];
            ss[t >> 2] += v * a_s[t * 16 + c];
            sd[t >> 2] += v * a_d[t * 16 + c];
        }
#pragma unroll
        for (int h = 0; h < 4; h++) {
#pragma unroll
            for (int off = 1; off <= 8; off <<= 1) {
                ss[h] += __shfl_xor(ss[h], off, 16);
                sd[h] += __shfl_xor(sd[h], off, 16);
            }
        }
        if (c == i && r < M) {
            *(float4*)(ssrc + (size_t)r * 4) = make_float4(ss[0], ss[1], ss[2], ss[3]);
            *(float4*)(sdst + (size_t)r * 4) = make_float4(sd[0], sd[1], sd[2], sd[3]);
        }
    }

#pragma unroll
    for (int i = 0; i < 4; i++) {
        int r = row_base + q * 4 + i;
        if (r < M) {
            float sc = dinv[r];
#pragma unroll
            for (int t = 0; t < 4; t++)
                Ch1[(size_t)r * 64 + t * 16 + c] = f2bf(acc[t][i] * sc);
#pragma unroll
            for (int t = 0; t < 16; t++)
                Chg[(size_t)r * 256 + t * 16 + c] = f2bf(acc[t + 4][i]);
        }
    }
}

// ---------------------------------------------------------------------------
// N=16 MFMA GEMM body (device, inlined). A exact bf16; W2 hi/lo -> 2 MFMAs.
// Output bf16 into the INTERLEAVED pair buffer at [(r*16+c)*2 + OFS].
// ---------------------------------------------------------------------------
template <int KB, bool SCALE, bool SC2, int OFS>
__device__ inline void n16_body(int bx, int tid,
                                const unsigned short* __restrict__ A,
                                const unsigned short* __restrict__ Bhi,
                                const unsigned short* __restrict__ Blo,
                                unsigned short* __restrict__ Cbf,
                                const float* __restrict__ rowscale,
                                const float* __restrict__ a_s2,
                                const float* __restrict__ a_d2,
                                float* __restrict__ s2s,
                                float* __restrict__ s2d, int M) {
    const int K = KB * 32;
    int w = tid >> 6, lane = tid & 63, q = lane >> 4, c = lane & 15;
    int row_base = bx * 64 + w * 16;
    int ar = min(row_base + c, M - 1);
    const unsigned short* ap = A + (size_t)ar * K + q * 8;
    f32x4 acc = (f32x4){0.f, 0.f, 0.f, 0.f};
#pragma unroll
    for (int kb = 0; kb < KB; kb++) {
        short8 av = *(const short8*)(ap + kb * 32);
        size_t bo = ((size_t)kb * 64 + lane) * 8;
        short8 bh = *(const short8*)(Bhi + bo);
        short8 bl = *(const short8*)(Blo + bo);
        acc = __builtin_amdgcn_mfma_f32_16x16x32_bf16(av, bh, acc, 0, 0, 0);
        acc = __builtin_amdgcn_mfma_f32_16x16x32_bf16(av, bl, acc, 0, 0, 0);
    }
    if (SC2) {
#pragma unroll
        for (int i = 0; i < 4; i++) {
            float ps = acc[i] * a_s2[c];
            float pd = acc[i] * a_d2[c];
#pragma unroll
            for (int off = 1; off <= 8; off <<= 1) {
                ps += __shfl_xor(ps, off, 16);
                pd += __shfl_xor(pd, off, 16);
            }
            int r = row_base + q * 4 + i;
            if (c == i && r < M) {
                s2s[r] = ps;
                s2d[r] = pd;
            }
        }
    }
#pragma unroll
    for (int i = 0; i < 4; i++) {
        int r = row_base + q * 4 + i;
        if (r < M) {
            float sc = SCALE ? rowscale[r] : 1.0f;
            Cbf[((size_t)r * 16 + c) * 2 + OFS] = f2bf(acc[i] * sc);
        }
    }
}

// Both small GEMMs in one launch: blocks [0,GB) = GAT (K=256, fused s2),
// blocks [GB,2GB) = GCN (K=64, dinv-scaled). Branch is block-uniform.
__global__ __launch_bounds__(256) void mfma_n16_both(const unsigned short* __restrict__ Ag,
                                                     const unsigned short* __restrict__ Ac,
                                                     const unsigned short* __restrict__ bhiA2,
                                                     const unsigned short* __restrict__ bloA2,
                                                     const unsigned short* __restrict__ bhiG2,
                                                     const unsigned short* __restrict__ bloG2,
                                                     unsigned short* __restrict__ pairb,
                                                     const float* __restrict__ dinv,
                                                     const float* __restrict__ a_s2,
                                                     const float* __restrict__ a_d2,
                                                     float* __restrict__ s2s,
                                                     float* __restrict__ s2d,
                                                     int M, int GB) {
    int bx = blockIdx.x;
    if (bx < GB)
        n16_body<8, false, true, 1>(bx, threadIdx.x, Ag, bhiA2, bloA2, pairb,
                                    nullptr, a_s2, a_d2, s2s, s2d, M);
    else
        n16_body<2, true, false, 0>(bx - GB, threadIdx.x, Ac, bhiG2, bloG2, pairb,
                                    dinv, nullptr, nullptr, nullptr, nullptr, M);
}

// ---------------------------------------------------------------------------
// FUSED layer-1 aggregation: GAT1 (LDS-staged p/src, 4-edge unrolled
// gather, fabric-floor bound) + GCN1 riding the same CSR walk via sl[]
// (each 16-lane group handles its stride-4 edge subset, butterfly-reduced).
// Round-13: merges gcn1_agg (shared col loads + one launch fewer).
// ---------------------------------------------------------------------------
__global__ __launch_bounds__(256) void both_agg(const unsigned short* __restrict__ hg,
                                                const unsigned short* __restrict__ h1,
                                                const int* __restrict__ rs,
                                                const int* __restrict__ col,
                                                const float* __restrict__ ssrc,
                                                const float* __restrict__ sdst,
                                                const float* __restrict__ dinv,
                                                const float* __restrict__ bgat,
                                                const float* __restrict__ bgcn,
                                                unsigned short* __restrict__ outg,
                                                unsigned short* __restrict__ outc) {
    __shared__ int s_lds[4][64];
    __shared__ float p_lds[4][64 * 4];
    int tid = threadIdx.x;
    int w = tid >> 6, lane = tid & 63;
    int wid = blockIdx.x * 4 + w;       // grid exact: 12500*4 = NN
    int hh = lane >> 4;
    int cidx = (lane & 15) * 4;
    int* sl = s_lds[w];
    float* pl = p_lds[w];

    float di = dinv[wid];
    float4 sd4 = *(const float4*)(sdst + (size_t)wid * 4);
    float sdv[4] = {sd4.x, sd4.y, sd4.z, sd4.w};
    float4 sf4 = *(const float4*)(ssrc + (size_t)wid * 4);
    float sfv[4] = {sf4.x, sf4.y, sf4.z, sf4.w};
    float psf[4];
#pragma unroll
    for (int h = 0; h < 4; h++) {
        float e = sfv[h] + sdv[h];
        e = (e >= 0.f) ? e : 0.2f * e;
        psf[h] = __expf(e);
    }
    float pse = (hh & 2) ? ((hh & 1) ? psf[3] : psf[2]) : ((hh & 1) ? psf[1] : psf[0]);
    const unsigned short* hbase = hg + lane * 4;
    ushort4 hvs = *(const ushort4*)(hbase + (size_t)wid * 256);
    float4 acc;
    acc.x = bf2f(hvs.x) * pse; acc.y = bf2f(hvs.y) * pse;
    acc.z = bf2f(hvs.z) * pse; acc.w = bf2f(hvs.w) * pse;
    float4 accc = make_float4(0.f, 0.f, 0.f, 0.f);   // GCN accumulator

    float lsum[4] = {0.f, 0.f, 0.f, 0.f};
    int beg = rs[wid], end = rs[wid + 1];
    for (int j0 = beg; j0 < end; j0 += 64) {
        int cnt = min(64, end - j0);
        if (lane < cnt) {
            int sreg = col[j0 + lane];
            float4 sv = *(const float4*)(ssrc + (size_t)sreg * 4);
            float svv[4] = {sv.x, sv.y, sv.z, sv.w};
            float pv[4];
#pragma unroll
            for (int h = 0; h < 4; h++) {
                float e = svv[h] + sdv[h];
                e = (e >= 0.f) ? e : 0.2f * e;
                pv[h] = __expf(e);
                lsum[h] += pv[h];
            }
            sl[lane] = sreg;
            *(float4*)&pl[lane * 4] = make_float4(pv[0], pv[1], pv[2], pv[3]);
        }
        // same-wave LDS write->read: DS pipe in-order per wave, no barrier
        int e = 0;
        for (; e + 4 <= cnt; e += 4) {
            int s0 = sl[e], s1 = sl[e + 1], s2 = sl[e + 2], s3 = sl[e + 3];
            float p0 = pl[e * 4 + hh], p1 = pl[(e + 1) * 4 + hh];
            float p2 = pl[(e + 2) * 4 + hh], p3 = pl[(e + 3) * 4 + hh];
            ushort4 h0 = *(const ushort4*)(hbase + (size_t)s0 * 256);
            ushort4 h1v = *(const ushort4*)(hbase + (size_t)s1 * 256);
            ushort4 h2 = *(const ushort4*)(hbase + (size_t)s2 * 256);
            ushort4 h3 = *(const ushort4*)(hbase + (size_t)s3 * 256);
            acc.x += bf2f(h0.x) * p0; acc.y += bf2f(h0.y) * p0;
            acc.z += bf2f(h0.z) * p0; acc.w += bf2f(h0.w) * p0;
            acc.x += bf2f(h1v.x) * p1; acc.y += bf2f(h1v.y) * p1;
            acc.z += bf2f(h1v.z) * p1; acc.w += bf2f(h1v.w) * p1;
            acc.x += bf2f(h2.x) * p2; acc.y += bf2f(h2.y) * p2;
            acc.z += bf2f(h2.z) * p2; acc.w += bf2f(h2.w) * p2;
            acc.x += bf2f(h3.x) * p3; acc.y += bf2f(h3.y) * p3;
            acc.z += bf2f(h3.z) * p3; acc.w += bf2f(h3.w) * p3;
        }
        for (; e < cnt; e++) {
            int s = sl[e];
            float p = pl[e * 4 + hh];
            ushort4 hv = *(const ushort4*)(hbase + (size_t)s * 256);
            acc.x += bf2f(hv.x) * p; acc.y += bf2f(hv.y) * p;
            acc.z += bf2f(hv.z) * p; acc.w += bf2f(hv.w) * p;
        }
        // GCN gather: group hh handles edges {hh, hh+4, ...}, 2 in flight
        int e2 = hh;
        for (; e2 + 4 < cnt; e2 += 8) {
            int sa = sl[e2], sb = sl[e2 + 4];
            ushort4 va = *(const ushort4*)(h1 + (size_t)sa * HH + cidx);
            ushort4 vb = *(const ushort4*)(h1 + (size_t)sb * HH + cidx);
            accc.x += bf2f(va.x) + bf2f(vb.x);
            accc.y += bf2f(va.y) + bf2f(vb.y);
            accc.z += bf2f(va.z) + bf2f(vb.z);
            accc.w += bf2f(va.w) + bf2f(vb.w);
        }
        if (e2 < cnt) {
            int sa = sl[e2];
            ushort4 va = *(const ushort4*)(h1 + (size_t)sa * HH + cidx);
            accc.x += bf2f(va.x); accc.y += bf2f(va.y);
            accc.z += bf2f(va.z); accc.w += bf2f(va.w);
        }
    }
    // GAT epilogue
#pragma unroll
    for (int h = 0; h < 4; h++) {
        float v = lsum[h];
        for (int off = 32; off >= 1; off >>= 1) v += __shfl_xor(v, off, 64);
        lsum[h] = v + psf[h];
    }
    float lt = (hh & 2) ? ((hh & 1) ? lsum[3] : lsum[2]) : ((hh & 1) ? lsum[1] : lsum[0]);
    float li = 1.0f / lt;
    float4 bv = *(const float4*)(bgat + lane * 4);
    ushort4 o;
    o.x = f2bf(fmaxf(acc.x * li + bv.x, 0.f));
    o.y = f2bf(fmaxf(acc.y * li + bv.y, 0.f));
    o.z = f2bf(fmaxf(acc.z * li + bv.z, 0.f));
    o.w = f2bf(fmaxf(acc.w * li + bv.w, 0.f));
    *(ushort4*)(outg + (size_t)wid * 256 + lane * 4) = o;
    // GCN epilogue: reduce across the 4 groups (wave-uniform flow)
#pragma unroll
    for (int off = 16; off <= 32; off <<= 1) {
        accc.x += __shfl_xor(accc.x, off, 64);
        accc.y += __shfl_xor(accc.y, off, 64);
        accc.z += __shfl_xor(accc.z, off, 64);
        accc.w += __shfl_xor(accc.w, off, 64);
    }
    if (hh == 0) {
        ushort4 sv = *(const ushort4*)(h1 + (size_t)wid * HH + cidx);
        float4 bc = *(const float4*)(bgcn + cidx);
        ushort4 oc;
        oc.x = f2bf(fmaxf((accc.x + bf2f(sv.x)) * di + bc.x, 0.f));
        oc.y = f2bf(fmaxf((accc.y + bf2f(sv.y)) * di + bc.y, 0.f));
        oc.z = f2bf(fmaxf((accc.z + bf2f(sv.z)) * di + bc.z, 0.f));
        oc.w = f2bf(fmaxf((accc.w + bf2f(sv.w)) * di + bc.w, 0.f));
        *(ushort4*)(outc + (size_t)wid * HH + cidx) = oc;
    }
}

// ---------------------------------------------------------------------------
// Final aggregation: fused GCN2 + GAT2 over the interleaved pair buffer.
// ---------------------------------------------------------------------------
__global__ __launch_bounds__(256) void final_agg(const unsigned* __restrict__ hp,
                                                 const int* __restrict__ rs,
                                                 const int* __restrict__ col,
                                                 const float* __restrict__ dinv,
                                                 const float* __restrict__ s2s,
                                                 const float* __restrict__ s2d,
                                                 const float* __restrict__ bg2,
                                                 const float* __restrict__ bga2,
                                                 float* __restrict__ out) {
    int t = blockIdx.x * 256 + threadIdx.x;
    int node = t >> 4;
    int c = t & 15;
    float di = dinv[node];
    float sd = s2d[node];
    float es = s2s[node] + sd;
    es = (es >= 0.f) ? es : 0.2f * es;
    float psf = __expf(es);
    unsigned pvs = hp[(size_t)node * 16 + c];
    float accg = bf2f((unsigned short)pvs);
    float acca = bf2f((unsigned short)(pvs >> 16)) * psf;
    float lp = 0.f;
    int beg = rs[node], end = rs[node + 1];
    for (int j0 = beg; j0 < end; j0 += 16) {
        int cnt = min(16, end - j0);
        int sreg = 0;
        float pr = 0.f;
        if (c < cnt) {
            sreg = col[j0 + c];
            float e = s2s[sreg] + sd;
            e = (e >= 0.f) ? e : 0.2f * e;
            pr = __expf(e);
            lp += pr;
        }
        for (int e = 0; e < cnt; e += 4) {
            int si[4];
            float pi[4];
#pragma unroll
            for (int u = 0; u < 4; u++) {
                si[u] = __shfl(sreg, (e + u) & 15, 16);
                pi[u] = __shfl(pr, (e + u) & 15, 16);
            }
            unsigned hv[4];
#pragma unroll
            for (int u = 0; u < 4; u++) hv[u] = hp[(size_t)si[u] * 16 + c];
#pragma unroll
            for (int u = 0; u < 4; u++) {
                if (e + u < cnt) {
                    accg += bf2f((unsigned short)hv[u]);
                    acca += bf2f((unsigned short)(hv[u] >> 16)) * pi[u];
                }
            }
        }
    }
    for (int off = 8; off >= 1; off >>= 1) lp += __shfl_xor(lp, off, 16);
    float l = lp + psf;
    out[(size_t)node * 32 + c] = accg * di + bg2[c];
    out[(size_t)node * 32 + 16 + c] = acca / l + bga2[c];
}

// ---------------------------------------------------------------------------
// Launch
// ---------------------------------------------------------------------------
extern "C" void kernel_launch(void* const* d_in, const int* in_sizes, int n_in,
                              void* d_out, int out_size, void* d_ws, size_t ws_size,
                              hipStream_t stream) {
    const float* x      = (const float*)d_in[0];
    const int*   ei     = (const int*)d_in[1];
    const float* Wg1    = (const float*)d_in[2];
    const float* bg1    = (const float*)d_in[3];
    const float* Wg2    = (const float*)d_in[4];
    const float* bg2    = (const float*)d_in[5];
    const float* Wgat1  = (const float*)d_in[6];
    const float* a_src1 = (const float*)d_in[7];
    const float* a_dst1 = (const float*)d_in[8];
    const float* bgat1  = (const float*)d_in[9];
    const float* Wgat2  = (const float*)d_in[10];
    const float* a_src2 = (const float*)d_in[11];
    const float* a_dst2 = (const float*)d_in[12];
    const float* bgat2  = (const float*)d_in[13];
    float* out = (float*)d_out;

    const int* e_src = ei;
    const int* e_dst = ei + EE;

    char* wsb = (char*)d_ws;
    size_t o = 0;
    auto alloc = [&](size_t bytes) -> void* {
        void* p = wsb + o;
        o += (bytes + 255) & ~(size_t)255;
        return p;
    };
    float* dinv            = (float*)alloc(NN * 4);
    float* ssrc1           = (float*)alloc((size_t)NN * 16);
    float* sdst1           = (float*)alloc((size_t)NN * 16);
    unsigned short* h1b    = (unsigned short*)alloc((size_t)NN * HH * 2);
    unsigned short* xg1    = (unsigned short*)alloc((size_t)NN * HH * 2);
    unsigned short* hgb    = (unsigned short*)alloc((size_t)NN * 256 * 2);
    unsigned short* xgat1  = (unsigned short*)alloc((size_t)NN * 256 * 2);
    unsigned short* pairb  = (unsigned short*)alloc((size_t)NN * 16 * 4);  // interleaved h2|h2g
    float* s2src           = (float*)alloc(NN * 4);
    float* s2dst           = (float*)alloc(NN * 4);
    unsigned short* bhiC   = (unsigned short*)alloc((size_t)8 * NTT * 512 * 2);  // Wg1+Wgat1 (hi only)
    unsigned short* bhiG2  = (unsigned short*)alloc(64 * 16 * 2);
    unsigned short* bloG2  = (unsigned short*)alloc(64 * 16 * 2);
    unsigned short* bhiA2  = (unsigned short*)alloc(256 * 16 * 2);
    unsigned short* bloA2  = (unsigned short*)alloc(256 * 16 * 2);
    int* cnt               = (int*)alloc(NN * 4);
    int* rowstart          = (int*)alloc((NN + 1) * 4);
    int* cursor            = (int*)alloc(NN * 4);
    int* colarr            = (int*)alloc((size_t)EE * 4);
    int* partial           = (int*)alloc(256 * 4);
    int* blockoff          = (int*)alloc(256 * 4);

    const int TB = 256;
    const int NB = (NN + 255) / 256;
    // CSR build + weight packing
    k_zero_int<<<(NN + TB - 1) / TB, TB, 0, stream>>>(cnt, NN);
    k_count<<<(EE + TB - 1) / TB, TB, 0, stream>>>(e_dst, cnt, EE);
    k_scan_a<<<NB, TB, 0, stream>>>(cnt, partial, NN);
    k_scan_b<<<1, TB, 0, stream>>>(partial, blockoff, rowstart + NN, NB);
    k_scan_c<<<NB, TB, 0, stream>>>(cnt, blockoff, rowstart, cursor, dinv, NN);
    k_fill<<<(EE + TB - 1) / TB, TB, 0, stream>>>(e_src, e_dst, cursor, colarr, EE);
    k_pack_all<<<(10880 + TB - 1) / TB, TB, 0, stream>>>(Wg1, Wgat1, Wg2, Wgat2,
                                                         bhiC, bhiG2, bloG2,
                                                         bhiA2, bloA2);

    const int GB = (NN + 63) / 64;    // 782
    const int G16 = (NN * 16) / 256;  // exact: 3125

    // Fused big GEMM: h1b (scaled) + hgb + s1 scores in ONE pass over x
    mfma_gemm_fused<<<GB, TB, 0, stream>>>(x, bhiC, h1b, hgb, dinv,
                                           a_src1, a_dst1, ssrc1, sdst1, NN);

    // Fused GCN1+GAT1 aggregation
    both_agg<<<NN / 4, TB, 0, stream>>>(hgb, h1b, rowstart, colarr, ssrc1, sdst1,
                                        dinv, bgat1, bg1, xgat1, xg1);

    // Both small GEMMs in one launch
    mfma_n16_both<<<2 * GB, TB, 0, stream>>>(xgat1, xg1, bhiA2, bloA2, bhiG2, bloG2,
                                             pairb, dinv, a_src2, a_dst2,
                                             s2src, s2dst, NN, GB);

    // Fused GCN2+GAT2 aggregation -> d_out
    final_agg<<<G16, TB, 0, stream>>>((const unsigned*)pairb, rowstart, colarr, dinv,
                                      s2src, s2dst, bg2, bgat2, out);
}